// Round 3
// baseline (463.434 us; speedup 1.0000x reference)
//
#include <hip/hip_runtime.h>
#include <hip/hip_fp16.h>
#include <math.h>

typedef _Float16 f16;
typedef _Float16 half8_t __attribute__((ext_vector_type(8)));
typedef _Float16 half4_t __attribute__((ext_vector_type(4)));
typedef _Float16 half2_t __attribute__((ext_vector_type(2)));
typedef __fp16   fp16x2  __attribute__((ext_vector_type(2)));
typedef float    float4_t __attribute__((ext_vector_type(4)));

// Converted weights (f16), written once per call by convert_w_kernel.
__device__ f16 Wh[1024 * 1024];

__device__ __forceinline__ void gl_lds16(const void* g, void* l) {
    __builtin_amdgcn_global_load_lds(
        (const __attribute__((address_space(1))) void*)g,
        (__attribute__((address_space(3))) void*)l,
        16, 0, 0);
}

__device__ __forceinline__ half2_t pkrtz(float a, float b) {
    fp16x2 r = __builtin_amdgcn_cvt_pkrtz(a, b);
    return __builtin_bit_cast(half2_t, r);
}

__device__ __forceinline__ half8_t cvt8(float4_t lo, float4_t hi) {
    half2_t p0 = pkrtz(lo[0], lo[1]);
    half2_t p1 = pkrtz(lo[2], lo[3]);
    half2_t p2 = pkrtz(hi[0], hi[1]);
    half2_t p3 = pkrtz(hi[2], hi[3]);
    half8_t r;
    r[0] = p0[0]; r[1] = p0[1]; r[2] = p1[0]; r[3] = p1[1];
    r[4] = p2[0]; r[5] = p2[1]; r[6] = p3[0]; r[7] = p3[1];
    return r;
}

__global__ __launch_bounds__(256) void convert_w_kernel(const float* __restrict__ W) {
    const int i = (blockIdx.x * 256 + threadIdx.x) * 8;
    const float4_t a = *(const float4_t*)(W + i);
    const float4_t b = *(const float4_t*)(W + i + 4);
    half8_t h;  // RTN conversion (accuracy; this kernel is cold)
#pragma unroll
    for (int t = 0; t < 4; ++t) h[t] = (f16)a[t];
#pragma unroll
    for (int t = 0; t < 4; ++t) h[4 + t] = (f16)b[t];
    *(half8_t*)(Wh + i) = h;
}

// ---------------------------------------------------------------------------
// 256x256 tile, BK=64, 8 waves (512 thr), double-buffered LDS (128 KB).
// Counted vmcnt: for AF32 the A register-loads are issued BEFORE B's
// global_load_lds so the compiler's wait at each writeA32 is vmcnt(8)/vmcnt(4)
// and B's gl_lds are NEVER drained mid-iteration (round-2 post-mortem: the
// old order forced vmcnt(0) twice per K-tile).
// ---------------------------------------------------------------------------

__device__ __forceinline__ void stage16(const f16* __restrict__ base, f16* dst,
                                        int tid, int kt) {
#pragma unroll
    for (int it = 0; it < 4; ++it) {
        const int ch = tid + it * 512;
        const int r = ch >> 3, s = ch & 7;
        gl_lds16(base + (size_t)r * 1024 + kt + ((s ^ (r & 7)) << 3), dst + ch * 8);
    }
}

__device__ __forceinline__ void loadA32(const float* __restrict__ base, int tid,
                                        int kt, int itbase, float4_t g[4]) {
#pragma unroll
    for (int it = 0; it < 2; ++it) {
        const int ch = tid + (itbase + it) * 512;
        const int r = ch >> 3, s = ch & 7;
        const float* p = base + (size_t)r * 1024 + kt + ((s ^ (r & 7)) << 3);
        g[2 * it]     = *(const float4_t*)p;
        g[2 * it + 1] = *(const float4_t*)(p + 4);
    }
}

__device__ __forceinline__ void writeA32(f16* dst, int tid, int itbase,
                                         const float4_t g[4]) {
#pragma unroll
    for (int it = 0; it < 2; ++it) {
        const int ch = tid + (itbase + it) * 512;
        *(half8_t*)(dst + ch * 8) = cvt8(g[2 * it], g[2 * it + 1]);
    }
}

template <typename TA, typename TC>
__device__ __forceinline__ void gemm_tile256(const TA* __restrict__ A,
                                             const float* __restrict__ bias,
                                             TC* __restrict__ C) {
    constexpr int K = 1024, N = 1024, NT = 16;  // NT = K/64
    constexpr bool AF32 = (sizeof(TA) == 4);
    __shared__ __align__(16) f16 smem[65536];  // 128 KB
    f16* const Asb = smem;          // [2][16384]
    f16* const Bsb = smem + 32768;  // [2][16384]

    const int tid  = threadIdx.x;
    const int lane = tid & 63;
    const int wave = tid >> 6;
    const int wr   = wave >> 2;  // 0..1
    const int wc   = wave & 3;   // 0..3
    const int lrow = lane & 15;
    const int kq   = lane >> 4;  // 0..3
    const int row0 = blockIdx.x * 256;
    const int col0 = blockIdx.y * 256;

    const f16*   Ag16 = nullptr;
    const float* Ag32 = nullptr;
    if constexpr (AF32) Ag32 = (const float*)A + (size_t)row0 * K;
    else                Ag16 = (const f16*)A + (size_t)row0 * K;
    const f16* const Bg = Wh + (size_t)col0 * K;

    float4_t acc[8][4];
#pragma unroll
    for (int i = 0; i < 8; ++i)
#pragma unroll
        for (int j = 0; j < 4; ++j)
            acc[i][j] = (float4_t){0.f, 0.f, 0.f, 0.f};

    // ---- prologue: tile 0 into buffer 0
    if constexpr (AF32) {
        stage16(Bg, Bsb, tid, 0);
        float4_t g0[4], g1[4];
        loadA32(Ag32, tid, 0, 0, g0);
        loadA32(Ag32, tid, 0, 2, g1);
        writeA32(Asb, tid, 0, g0);
        writeA32(Asb, tid, 2, g1);
        asm volatile("s_waitcnt vmcnt(0)" ::: "memory");   // B gl_lds landed
        asm volatile("s_waitcnt lgkmcnt(0)" ::: "memory"); // A ds_writes landed
    } else {
        stage16(Ag16, Asb, tid, 0);
        stage16(Bg, Bsb, tid, 0);
    }

    for (int u = 0; u < NT; ++u) {
        const int cur = u & 1;
        const f16* const Ac = Asb + (cur << 14);
        const f16* const Bc = Bsb + (cur << 14);
        f16* const An = Asb + ((cur ^ 1) << 14);
        f16* const Bn = Bsb + ((cur ^ 1) << 14);
        const int kn = ((u + 1) & (NT - 1)) * 64;  // last iter: dead re-stage

        // issue next-tile staging: A register loads FIRST (oldest), B gl_lds last
        float4_t ga0[4], ga1[4];
        if constexpr (AF32) {
            loadA32(Ag32, tid, kn, 0, ga0);   // 4 loads (oldest)
            loadA32(Ag32, tid, kn, 2, ga1);   // 4 loads
            stage16(Bg, Bn, tid, kn);         // 4 gl_lds (newest)
            asm volatile("s_waitcnt vmcnt(12)" ::: "memory");  // prev tile done
        } else {
            stage16(Ag16, An, tid, kn);       // 4 gl_lds
            stage16(Bg, Bn, tid, kn);         // 4 gl_lds
            asm volatile("s_waitcnt vmcnt(8)" ::: "memory");   // prev tile done
        }
        __builtin_amdgcn_s_barrier();

        // B fragments for the whole tile (8 x ds_read_b128, live both phases)
        half8_t bfv[4][2];
#pragma unroll
        for (int j = 0; j < 4; ++j) {
            const int n = wc * 64 + j * 16 + lrow;
#pragma unroll
            for (int ks = 0; ks < 2; ++ks)
                bfv[j][ks] = *(const half8_t*)(Bc + n * 64 + (((ks * 4 + kq) ^ (n & 7)) << 3));
        }

        // ---- phase 0: m-fragments 0..3
        {
            half8_t afv[4][2];
#pragma unroll
            for (int i = 0; i < 4; ++i) {
                const int m = wr * 128 + i * 16 + lrow;
#pragma unroll
                for (int ks = 0; ks < 2; ++ks)
                    afv[i][ks] = *(const half8_t*)(Ac + m * 64 + (((ks * 4 + kq) ^ (m & 7)) << 3));
            }
            __builtin_amdgcn_s_setprio(1);
#pragma unroll
            for (int i = 0; i < 4; ++i)
#pragma unroll
                for (int j = 0; j < 4; ++j)
#pragma unroll
                    for (int ks = 0; ks < 2; ++ks)
                        acc[i][j] = __builtin_amdgcn_mfma_f32_16x16x32_f16(
                            afv[i][ks], bfv[j][ks], acc[i][j], 0, 0, 0);
            __builtin_amdgcn_s_setprio(0);
        }

        if constexpr (AF32) {
            writeA32(An, tid, 0, ga0);  // compiler waits vmcnt(8): B+ga1 stay in flight
        }

        // ---- phase 1: m-fragments 4..7
        {
            half8_t afv[4][2];
#pragma unroll
            for (int i = 0; i < 4; ++i) {
                const int m = wr * 128 + (4 + i) * 16 + lrow;
#pragma unroll
                for (int ks = 0; ks < 2; ++ks)
                    afv[i][ks] = *(const half8_t*)(Ac + m * 64 + (((ks * 4 + kq) ^ (m & 7)) << 3));
            }
            __builtin_amdgcn_s_setprio(1);
#pragma unroll
            for (int i = 0; i < 4; ++i)
#pragma unroll
                for (int j = 0; j < 4; ++j)
#pragma unroll
                    for (int ks = 0; ks < 2; ++ks)
                        acc[4 + i][j] = __builtin_amdgcn_mfma_f32_16x16x32_f16(
                            afv[i][ks], bfv[j][ks], acc[4 + i][j], 0, 0, 0);
            __builtin_amdgcn_s_setprio(0);
        }

        if constexpr (AF32) {
            writeA32(An, tid, 2, ga1);  // compiler waits vmcnt(4): B stays in flight
        }
        asm volatile("s_waitcnt lgkmcnt(0)" ::: "memory");
        __builtin_amdgcn_s_barrier();
    }
    // drain the dead last-iteration staging before the block can retire
    asm volatile("s_waitcnt vmcnt(0)" ::: "memory");

    // Epilogue (proven): C/D layout col=lane&15, row=(lane>>4)*4+reg
    const int ccol  = lane & 15;
    const int rbase = (lane >> 4) << 2;
#pragma unroll
    for (int j = 0; j < 4; ++j) {
        const int gcol = col0 + wc * 64 + j * 16 + ccol;
        const float bv = bias[gcol];
#pragma unroll
        for (int i = 0; i < 8; ++i) {
#pragma unroll
            for (int r = 0; r < 4; ++r) {
                const int grow = row0 + wr * 128 + i * 16 + rbase + r;
                C[(size_t)grow * N + gcol] = (TC)(acc[i][j][r] + bv);
            }
        }
    }
}

template <typename TA, typename TC>
__global__ __launch_bounds__(512, 2) void gemm_kernel(
    const TA* __restrict__ A, const float* __restrict__ bias,
    TC* __restrict__ C) {
    gemm_tile256<TA, TC>(A, bias, C);
}

// Fused q/k/v projection: same W, independent outputs; blockIdx.z selects pair.
__global__ __launch_bounds__(512, 2) void gemm_proj_kernel(
    const float* __restrict__ q, const float* __restrict__ k,
    const float* __restrict__ v, const float* __restrict__ bias,
    f16* __restrict__ cq, f16* __restrict__ ck, f16* __restrict__ cv) {
    const int z = blockIdx.z;
    const float* A = (z == 0) ? q : (z == 1) ? k : v;
    f16*         C = (z == 0) ? cq : (z == 1) ? ck : cv;
    gemm_tile256<float, f16>(A, bias, C);
}

// ---------------------------------------------------------------------------
// MFMA attention.  One wave per (b,s) pair, 4 pairs per block.
// Swapped QK^T: S[e][d] = sum_h K[h][e] Q[h][d] via mfma_f32_16x16x16f16
// (A = K-frag from transposed Ks, B = Q-frag from transposed Qs).
// C-layout: lane(g=l>>4, lc=l&15) holds S[e=16et+4g+r][d=16dt+lc] -- which is
// EXACTLY the PV A-fragment layout A[m=lc][k=4g+r] for 16x16x16: no transpose.
// Softmax row-reduce: 16 in-lane values + shfl_xor(16) + shfl_xor(32);
// 1/sum folded into P before the f16 pack.  Output staged through LDS so each
// wave stores 8 full 128-B lines (was: 64 scattered 16-B chunks).
// LDS read traffic per wave: ~8 KB (was ~256 KB of broadcast reads).
// ---------------------------------------------------------------------------
__global__ __launch_bounds__(256) void attn_kernel(
    const f16* __restrict__ pq, const f16* __restrict__ pk,
    const f16* __restrict__ pv, f16* __restrict__ outp)
{
    __shared__ __align__(16) f16 Qs[4][64][24];  // [wave][d][h] (transposed)
    __shared__ __align__(16) f16 Ks[4][64][24];  // [wave][e][h] (transposed)
    __shared__ __align__(16) f16 Vs[4][16][72];  // [wave][h][e]
    __shared__ __align__(16) f16 Os[4][64][24];  // [wave][d][h] output stage
    const int lane = threadIdx.x & 63;
    const int wave = threadIdx.x >> 6;
    const int p0 = blockIdx.x * 4;
    const int p = p0 + wave;
    const f16* qptr = pq + (size_t)p * 1024;
    const f16* kptr = pk + (size_t)p * 1024;
    const f16* vptr = pv + (size_t)p * 1024;

    // Stage: lane covers global halves [lane*16, +16): h = lane>>2,
    // d/e in [(lane&3)*16, +16).  Q and K transposed, V straight.
    {
        const int h  = lane >> 2;
        const int c0 = (lane & 3) << 4;
        const half8_t q0 = *(const half8_t*)(qptr + lane * 16);
        const half8_t q1 = *(const half8_t*)(qptr + lane * 16 + 8);
        const half8_t k0 = *(const half8_t*)(kptr + lane * 16);
        const half8_t k1 = *(const half8_t*)(kptr + lane * 16 + 8);
#pragma unroll
        for (int t = 0; t < 8; ++t) {
            Qs[wave][c0 + t][h]     = q0[t];
            Qs[wave][c0 + 8 + t][h] = q1[t];
            Ks[wave][c0 + t][h]     = k0[t];
            Ks[wave][c0 + 8 + t][h] = k1[t];
        }
        const half8_t v0 = *(const half8_t*)(vptr + lane * 16);
        const half8_t v1 = *(const half8_t*)(vptr + lane * 16 + 8);
        *(half8_t*)&Vs[wave][h][c0]     = v0;
        *(half8_t*)&Vs[wave][h][c0 + 8] = v1;
    }
    __syncthreads();

    const int g  = lane >> 4;   // 0..3
    const int lc = lane & 15;   // 0..15

    // ---- QK^T (swapped): 16 x mfma 16x16x16, fragments read once (b64 each)
    half4_t ka[4], qb[4];
#pragma unroll
    for (int t = 0; t < 4; ++t) {
        ka[t] = *(const half4_t*)&Ks[wave][16 * t + lc][4 * g];
        qb[t] = *(const half4_t*)&Qs[wave][16 * t + lc][4 * g];
    }
    float4_t s[4][4];  // [et][dt]
#pragma unroll
    for (int et = 0; et < 4; ++et)
#pragma unroll
        for (int dt = 0; dt < 4; ++dt)
            s[et][dt] = __builtin_amdgcn_mfma_f32_16x16x16f16(
                ka[et], qb[dt], (float4_t){0.f, 0.f, 0.f, 0.f}, 0, 0, 0);

    // ---- softmax over e for each of the 4 in-lane d-columns (d = 16dt+lc)
    float inv[4];
#pragma unroll
    for (int dt = 0; dt < 4; ++dt) {
        float m = s[0][dt][0];
#pragma unroll
        for (int et = 0; et < 4; ++et)
#pragma unroll
            for (int r = 0; r < 4; ++r) m = fmaxf(m, s[et][dt][r]);
        m = fmaxf(m, __shfl_xor(m, 16));
        m = fmaxf(m, __shfl_xor(m, 32));
        float sum = 0.f;
#pragma unroll
        for (int et = 0; et < 4; ++et)
#pragma unroll
            for (int r = 0; r < 4; ++r) {
                const float t = __expf((s[et][dt][r] - m) * 0.125f);
                s[et][dt][r] = t;
                sum += t;
            }
        sum += __shfl_xor(sum, 16);
        sum += __shfl_xor(sum, 32);
        inv[dt] = 1.f / sum;
    }

    // ---- P -> f16 A-fragments (inv folded in); layout identity: pa[kt][dt]
    half4_t pa[4][4];
#pragma unroll
    for (int kt = 0; kt < 4; ++kt)
#pragma unroll
        for (int dt = 0; dt < 4; ++dt) {
            const half2_t lo = pkrtz(s[kt][dt][0] * inv[dt], s[kt][dt][1] * inv[dt]);
            const half2_t hi = pkrtz(s[kt][dt][2] * inv[dt], s[kt][dt][3] * inv[dt]);
            half4_t f;
            f[0] = lo[0]; f[1] = lo[1]; f[2] = hi[0]; f[3] = hi[1];
            pa[kt][dt] = f;
        }

    // ---- PV: C2[d][h] = sum_e P[d][e] V[h][e]; 16 x mfma 16x16x16
    float4_t o[4];
#pragma unroll
    for (int dt = 0; dt < 4; ++dt) o[dt] = (float4_t){0.f, 0.f, 0.f, 0.f};
#pragma unroll
    for (int kt = 0; kt < 4; ++kt) {
        const half4_t vb = *(const half4_t*)&Vs[wave][lc][16 * kt + 4 * g];
#pragma unroll
        for (int dt = 0; dt < 4; ++dt)
            o[dt] = __builtin_amdgcn_mfma_f32_16x16x16f16(pa[kt][dt], vb, o[dt], 0, 0, 0);
    }

    // ---- stage output: C2 col = h = lc, row(d) = 16dt + 4g + r
#pragma unroll
    for (int dt = 0; dt < 4; ++dt)
#pragma unroll
        for (int r = 0; r < 4; ++r)
            Os[wave][16 * dt + 4 * g + r][lc] = (f16)o[dt][r];
    __syncthreads();

    // ---- coalesced store: unit u = one 16-B chunk; wave covers 8 full lines
    const int b0 = p0 >> 11;
    const int s0 = p0 & 2047;
#pragma unroll
    for (int hf = 0; hf < 2; ++hf) {
        const int u  = threadIdx.x + hf * 256;
        const int d  = u >> 3;
        const int si = (u >> 1) & 3;
        const int uh = u & 1;
        const half8_t val = *(const half8_t*)&Os[si][d][uh * 8];
        f16* dst = outp + ((size_t)(b0 * 64 + d) * 2048 + (s0 + si)) * 16 + uh * 8;
        *(half8_t*)dst = val;
    }
}

extern "C" void kernel_launch(void* const* d_in, const int* in_sizes, int n_in,
                              void* d_out, int out_size, void* d_ws, size_t ws_size,
                              hipStream_t stream)
{
    const float* q    = (const float*)d_in[0];
    const float* k    = (const float*)d_in[1];
    const float* v    = (const float*)d_in[2];
    const float* W    = (const float*)d_in[3];
    const float* bias = (const float*)d_in[4];
    float* out = (float*)d_out;

    const int M = 16384;
    const size_t elems = (size_t)M * 1024;

    // ws: projq (32MB f16) + attn_out (32MB f16). projk/projv parked inside
    // d_out (64MB fp32), consumed by attn before the final GEMM overwrites it.
    f16* projq = (f16*)d_ws;
    f16* attn  = projq + elems;
    f16* projk = (f16*)d_out;
    f16* projv = projk + elems;

    convert_w_kernel<<<512, 256, 0, stream>>>(W);

    dim3 gridp(M / 256, 1024 / 256, 3);  // fused q/k/v projections
    gemm_proj_kernel<<<gridp, 512, 0, stream>>>(q, k, v, bias, projq, projk, projv);
    attn_kernel<<<M / 4, 256, 0, stream>>>(projq, projk, projv, attn);
    dim3 gridf(M / 256, 1024 / 256);
    gemm_kernel<f16, float><<<gridf, 512, 0, stream>>>(attn, bias, out);
}

// Round 4
// 446.352 us; speedup vs baseline: 1.0383x; 1.0383x over previous
//
#include <hip/hip_runtime.h>
#include <hip/hip_fp16.h>
#include <math.h>

typedef _Float16 f16;
typedef _Float16 half8_t __attribute__((ext_vector_type(8)));
typedef _Float16 half4_t __attribute__((ext_vector_type(4)));
typedef _Float16 half2_t __attribute__((ext_vector_type(2)));
typedef __fp16   fp16x2  __attribute__((ext_vector_type(2)));
typedef float    float4_t __attribute__((ext_vector_type(4)));

// Converted weights (f16), written once per call by convert_w_kernel.
__device__ f16 Wh[1024 * 1024];
// Converted q/k/v (f16), written by convert_x_kernel (96 MB static).
__device__ f16 Xh[3ul * 16777216];

__device__ __forceinline__ void gl_lds16(const void* g, void* l) {
    __builtin_amdgcn_global_load_lds(
        (const __attribute__((address_space(1))) void*)g,
        (__attribute__((address_space(3))) void*)l,
        16, 0, 0);
}

__device__ __forceinline__ half2_t pkrtz(float a, float b) {
    fp16x2 r = __builtin_amdgcn_cvt_pkrtz(a, b);
    return __builtin_bit_cast(half2_t, r);
}

__device__ __forceinline__ half8_t cvt8(float4_t lo, float4_t hi) {
    half2_t p0 = pkrtz(lo[0], lo[1]);
    half2_t p1 = pkrtz(lo[2], lo[3]);
    half2_t p2 = pkrtz(hi[0], hi[1]);
    half2_t p3 = pkrtz(hi[2], hi[3]);
    half8_t r;
    r[0] = p0[0]; r[1] = p0[1]; r[2] = p1[0]; r[3] = p1[1];
    r[4] = p2[0]; r[5] = p2[1]; r[6] = p3[0]; r[7] = p3[1];
    return r;
}

__global__ __launch_bounds__(256) void convert_w_kernel(const float* __restrict__ W) {
    const int i = (blockIdx.x * 256 + threadIdx.x) * 8;
    const float4_t a = *(const float4_t*)(W + i);
    const float4_t b = *(const float4_t*)(W + i + 4);
    half8_t h;  // RTN conversion (accuracy; this kernel is cold)
#pragma unroll
    for (int t = 0; t < 4; ++t) h[t] = (f16)a[t];
#pragma unroll
    for (int t = 0; t < 4; ++t) h[4 + t] = (f16)b[t];
    *(half8_t*)(Wh + i) = h;
}

// q/k/v f32 -> f16 (pkrtz, same numerics as the old in-GEMM conversion).
// Memory-bound: 192 MB read + 96 MB write.
__global__ __launch_bounds__(256) void convert_x_kernel(
    const float* __restrict__ q, const float* __restrict__ k,
    const float* __restrict__ v)
{
    const int z = blockIdx.z;
    const float* src = (z == 0) ? q : (z == 1) ? k : v;
    f16* dst = Xh + (size_t)z * 16777216;
    const size_t i = ((size_t)blockIdx.x * 256 + threadIdx.x) * 8;
    const float4_t a = *(const float4_t*)(src + i);
    const float4_t b = *(const float4_t*)(src + i + 4);
    *(half8_t*)(dst + i) = cvt8(a, b);
}

// ---------------------------------------------------------------------------
// 256x256 tile, BK=64, 8 waves (512 thr), double-buffered LDS (128 KB),
// pure-f16 path: both operands via global_load_lds, ONE counted vmcnt(8) per
// K-tile (pipeline depth 1 tile, never drained in-loop), raw s_barrier.
// LDS chunk swizzle: 16B slot s at row r holds logical chunk s ^ (r&7) ->
// fragment ds_read_b128 is bank-uniform (0 conflicts, proven).
// Round-3 post-mortem: f32-A reg-staging spilled (WRITE_SIZE +20MB) -> A is
// now pre-converted to f16 by convert_x_kernel.
// ---------------------------------------------------------------------------

__device__ __forceinline__ void stage16(const f16* __restrict__ base, f16* dst,
                                        int tid, int kt) {
#pragma unroll
    for (int it = 0; it < 4; ++it) {
        const int ch = tid + it * 512;
        const int r = ch >> 3, s = ch & 7;
        gl_lds16(base + (size_t)r * 1024 + kt + ((s ^ (r & 7)) << 3), dst + ch * 8);
    }
}

template <typename TC>
__device__ __forceinline__ void gemm_tile256(const f16* __restrict__ A,
                                             const float* __restrict__ bias,
                                             TC* __restrict__ C,
                                             int row0, int col0) {
    constexpr int K = 1024, N = 1024, NT = 16;  // NT = K/64
    __shared__ __align__(16) f16 smem[65536];  // 128 KB -> 1 block/CU (LDS-bound)
    f16* const Asb = smem;          // [2][16384]
    f16* const Bsb = smem + 32768;  // [2][16384]

    const int tid  = threadIdx.x;
    const int lane = tid & 63;
    const int wave = tid >> 6;
    const int wr   = wave >> 2;  // 0..1
    const int wc   = wave & 3;   // 0..3
    const int lrow = lane & 15;
    const int kq   = lane >> 4;  // 0..3

    const f16* const Ag = A + (size_t)row0 * K;
    const f16* const Bg = Wh + (size_t)col0 * K;

    float4_t acc[8][4];
#pragma unroll
    for (int i = 0; i < 8; ++i)
#pragma unroll
        for (int j = 0; j < 4; ++j)
            acc[i][j] = (float4_t){0.f, 0.f, 0.f, 0.f};

    // ---- prologue: tile 0 into buffer 0 (8 gl_lds left in flight)
    stage16(Ag, Asb, tid, 0);
    stage16(Bg, Bsb, tid, 0);

    for (int u = 0; u < NT; ++u) {
        const int cur = u & 1;
        const f16* const Ac = Asb + (cur << 14);
        const f16* const Bc = Bsb + (cur << 14);
        f16* const An = Asb + ((cur ^ 1) << 14);
        f16* const Bn = Bsb + ((cur ^ 1) << 14);
        const int kn = ((u + 1) & (NT - 1)) * 64;  // last iter: dead re-stage

        // issue next-tile staging, then wait for PREVIOUS tile only (counted)
        stage16(Ag, An, tid, kn);  // 4 gl_lds
        stage16(Bg, Bn, tid, kn);  // 4 gl_lds
        asm volatile("s_waitcnt vmcnt(8)" ::: "memory");  // tile-u loads landed
        __builtin_amdgcn_s_barrier();

        // B fragments for the whole tile (8 x ds_read_b128, live both phases)
        half8_t bfv[4][2];
#pragma unroll
        for (int j = 0; j < 4; ++j) {
            const int n = wc * 64 + j * 16 + lrow;
#pragma unroll
            for (int ks = 0; ks < 2; ++ks)
                bfv[j][ks] = *(const half8_t*)(Bc + n * 64 + (((ks * 4 + kq) ^ (n & 7)) << 3));
        }

        // ---- phase 0: m-fragments 0..3
        {
            half8_t afv[4][2];
#pragma unroll
            for (int i = 0; i < 4; ++i) {
                const int m = wr * 128 + i * 16 + lrow;
#pragma unroll
                for (int ks = 0; ks < 2; ++ks)
                    afv[i][ks] = *(const half8_t*)(Ac + m * 64 + (((ks * 4 + kq) ^ (m & 7)) << 3));
            }
            __builtin_amdgcn_s_setprio(1);
#pragma unroll
            for (int i = 0; i < 4; ++i)
#pragma unroll
                for (int j = 0; j < 4; ++j)
#pragma unroll
                    for (int ks = 0; ks < 2; ++ks)
                        acc[i][j] = __builtin_amdgcn_mfma_f32_16x16x32_f16(
                            afv[i][ks], bfv[j][ks], acc[i][j], 0, 0, 0);
            __builtin_amdgcn_s_setprio(0);
        }

        // ---- phase 1: m-fragments 4..7
        {
            half8_t afv[4][2];
#pragma unroll
            for (int i = 0; i < 4; ++i) {
                const int m = wr * 128 + (4 + i) * 16 + lrow;
#pragma unroll
                for (int ks = 0; ks < 2; ++ks)
                    afv[i][ks] = *(const half8_t*)(Ac + m * 64 + (((ks * 4 + kq) ^ (m & 7)) << 3));
            }
            __builtin_amdgcn_s_setprio(1);
#pragma unroll
            for (int i = 0; i < 4; ++i)
#pragma unroll
                for (int j = 0; j < 4; ++j)
#pragma unroll
                    for (int ks = 0; ks < 2; ++ks)
                        acc[4 + i][j] = __builtin_amdgcn_mfma_f32_16x16x32_f16(
                            afv[i][ks], bfv[j][ks], acc[4 + i][j], 0, 0, 0);
            __builtin_amdgcn_s_setprio(0);
        }

        // own ds_reads done, then sync: buffer cur is free for iter u+1 staging
        asm volatile("s_waitcnt lgkmcnt(0)" ::: "memory");
        __builtin_amdgcn_s_barrier();
    }
    // drain the dead last-iteration staging before the block can retire
    asm volatile("s_waitcnt vmcnt(0)" ::: "memory");

    // Epilogue (proven): C/D layout col=lane&15, row=(lane>>4)*4+reg
    const int ccol  = lane & 15;
    const int rbase = (lane >> 4) << 2;
#pragma unroll
    for (int j = 0; j < 4; ++j) {
        const int gcol = col0 + wc * 64 + j * 16 + ccol;
        const float bv = bias[gcol];
#pragma unroll
        for (int i = 0; i < 8; ++i) {
#pragma unroll
            for (int r = 0; r < 4; ++r) {
                const int grow = row0 + wr * 128 + i * 16 + rbase + r;
                C[(size_t)grow * N + gcol] = (TC)(acc[i][j][r] + bv);
            }
        }
    }
}

// Final GEMM: grid (64,4).  XCD swizzle, y-fastest virtual order so the 4
// blocks sharing an A-panel land on the same XCD L2 (A re-read 4x -> ~1x).
template <typename TC>
__global__ __launch_bounds__(512, 2) void gemm_kernel(
    const f16* __restrict__ A, const float* __restrict__ bias,
    TC* __restrict__ C) {
    const int f    = blockIdx.x + 64 * blockIdx.y;   // 0..255, hw dispatch order
    const int virt = (f & 7) * 32 + (f >> 3);        // bijective (256 % 8 == 0)
    gemm_tile256<TC>(A, bias, C, ((virt >> 2) & 63) * 256, (virt & 3) * 256);
}

// Fused q/k/v projection: grid (64,4,3); same swizzle idea over 768 blocks.
__global__ __launch_bounds__(512, 2) void gemm_proj_kernel(
    const float* __restrict__ bias,
    f16* __restrict__ cq, f16* __restrict__ ck, f16* __restrict__ cv) {
    const int f    = blockIdx.x + 64 * (blockIdx.y + 4 * blockIdx.z);  // 0..767
    const int virt = (f & 7) * 96 + (f >> 3);        // bijective (768 % 8 == 0)
    const int y = virt & 3, x = (virt >> 2) & 63, z = virt >> 8;
    f16* C = (z == 0) ? cq : (z == 1) ? ck : cv;
    gemm_tile256<f16>(Xh + (size_t)z * 16777216, bias, C, x * 256, y * 256);
}

// ---------------------------------------------------------------------------
// MFMA attention.  One wave per (b,s) pair, 4 pairs per block.
// Swapped QK^T: S[e][d] = sum_h K[h][e] Q[h][d] via mfma_f32_16x16x16f16.
// C-layout (g=l>>4, lc=l&15): S[e=16et+4g+r][d=16dt+lc] == PV A-fragment
// layout A[m=lc][k=4g+r] -- no transpose.  Softmax: 16 in-lane + 2 shfl_xor.
// Output staged through LDS -> 8 full 128-B lines per wave.
// ---------------------------------------------------------------------------
__global__ __launch_bounds__(256) void attn_kernel(
    const f16* __restrict__ pq, const f16* __restrict__ pk,
    const f16* __restrict__ pv, f16* __restrict__ outp)
{
    __shared__ __align__(16) f16 Qs[4][64][24];  // [wave][d][h] (transposed)
    __shared__ __align__(16) f16 Ks[4][64][24];  // [wave][e][h] (transposed)
    __shared__ __align__(16) f16 Vs[4][16][72];  // [wave][h][e]
    __shared__ __align__(16) f16 Os[4][64][24];  // [wave][d][h] output stage
    const int lane = threadIdx.x & 63;
    const int wave = threadIdx.x >> 6;
    const int p0 = blockIdx.x * 4;
    const int p = p0 + wave;
    const f16* qptr = pq + (size_t)p * 1024;
    const f16* kptr = pk + (size_t)p * 1024;
    const f16* vptr = pv + (size_t)p * 1024;

    {
        const int h  = lane >> 2;
        const int c0 = (lane & 3) << 4;
        const half8_t q0 = *(const half8_t*)(qptr + lane * 16);
        const half8_t q1 = *(const half8_t*)(qptr + lane * 16 + 8);
        const half8_t k0 = *(const half8_t*)(kptr + lane * 16);
        const half8_t k1 = *(const half8_t*)(kptr + lane * 16 + 8);
#pragma unroll
        for (int t = 0; t < 8; ++t) {
            Qs[wave][c0 + t][h]     = q0[t];
            Qs[wave][c0 + 8 + t][h] = q1[t];
            Ks[wave][c0 + t][h]     = k0[t];
            Ks[wave][c0 + 8 + t][h] = k1[t];
        }
        const half8_t v0 = *(const half8_t*)(vptr + lane * 16);
        const half8_t v1 = *(const half8_t*)(vptr + lane * 16 + 8);
        *(half8_t*)&Vs[wave][h][c0]     = v0;
        *(half8_t*)&Vs[wave][h][c0 + 8] = v1;
    }
    __syncthreads();

    const int g  = lane >> 4;   // 0..3
    const int lc = lane & 15;   // 0..15

    // ---- QK^T (swapped): 16 x mfma 16x16x16
    half4_t ka[4], qb[4];
#pragma unroll
    for (int t = 0; t < 4; ++t) {
        ka[t] = *(const half4_t*)&Ks[wave][16 * t + lc][4 * g];
        qb[t] = *(const half4_t*)&Qs[wave][16 * t + lc][4 * g];
    }
    float4_t s[4][4];  // [et][dt]
#pragma unroll
    for (int et = 0; et < 4; ++et)
#pragma unroll
        for (int dt = 0; dt < 4; ++dt)
            s[et][dt] = __builtin_amdgcn_mfma_f32_16x16x16f16(
                ka[et], qb[dt], (float4_t){0.f, 0.f, 0.f, 0.f}, 0, 0, 0);

    // ---- softmax over e for each of the 4 in-lane d-columns (d = 16dt+lc)
    float inv[4];
#pragma unroll
    for (int dt = 0; dt < 4; ++dt) {
        float m = s[0][dt][0];
#pragma unroll
        for (int et = 0; et < 4; ++et)
#pragma unroll
            for (int r = 0; r < 4; ++r) m = fmaxf(m, s[et][dt][r]);
        m = fmaxf(m, __shfl_xor(m, 16));
        m = fmaxf(m, __shfl_xor(m, 32));
        float sum = 0.f;
#pragma unroll
        for (int et = 0; et < 4; ++et)
#pragma unroll
            for (int r = 0; r < 4; ++r) {
                const float t = __expf((s[et][dt][r] - m) * 0.125f);
                s[et][dt][r] = t;
                sum += t;
            }
        sum += __shfl_xor(sum, 16);
        sum += __shfl_xor(sum, 32);
        inv[dt] = 1.f / sum;
    }

    // ---- P -> f16 A-fragments (inv folded in); layout identity: pa[kt][dt]
    half4_t pa[4][4];
#pragma unroll
    for (int kt = 0; kt < 4; ++kt)
#pragma unroll
        for (int dt = 0; dt < 4; ++dt) {
            const half2_t lo = pkrtz(s[kt][dt][0] * inv[dt], s[kt][dt][1] * inv[dt]);
            const half2_t hi = pkrtz(s[kt][dt][2] * inv[dt], s[kt][dt][3] * inv[dt]);
            half4_t f;
            f[0] = lo[0]; f[1] = lo[1]; f[2] = hi[0]; f[3] = hi[1];
            pa[kt][dt] = f;
        }

    // ---- PV: C2[d][h] = sum_e P[d][e] V[h][e]; 16 x mfma 16x16x16
    float4_t o[4];
#pragma unroll
    for (int dt = 0; dt < 4; ++dt) o[dt] = (float4_t){0.f, 0.f, 0.f, 0.f};
#pragma unroll
    for (int kt = 0; kt < 4; ++kt) {
        const half4_t vb = *(const half4_t*)&Vs[wave][lc][16 * kt + 4 * g];
#pragma unroll
        for (int dt = 0; dt < 4; ++dt)
            o[dt] = __builtin_amdgcn_mfma_f32_16x16x16f16(pa[kt][dt], vb, o[dt], 0, 0, 0);
    }

    // ---- stage output: C2 col = h = lc, row(d) = 16dt + 4g + r
#pragma unroll
    for (int dt = 0; dt < 4; ++dt)
#pragma unroll
        for (int r = 0; r < 4; ++r)
            Os[wave][16 * dt + 4 * g + r][lc] = (f16)o[dt][r];
    __syncthreads();

    // ---- coalesced store: unit u = one 16-B chunk; wave covers 8 full lines
    const int b0 = p0 >> 11;
    const int s0 = p0 & 2047;
#pragma unroll
    for (int hf = 0; hf < 2; ++hf) {
        const int u  = threadIdx.x + hf * 256;
        const int d  = u >> 3;
        const int si = (u >> 1) & 3;
        const int uh = u & 1;
        const half8_t val = *(const half8_t*)&Os[si][d][uh * 8];
        f16* dst = outp + ((size_t)(b0 * 64 + d) * 2048 + (s0 + si)) * 16 + uh * 8;
        *(half8_t*)dst = val;
    }
}

extern "C" void kernel_launch(void* const* d_in, const int* in_sizes, int n_in,
                              void* d_out, int out_size, void* d_ws, size_t ws_size,
                              hipStream_t stream)
{
    const float* q    = (const float*)d_in[0];
    const float* k    = (const float*)d_in[1];
    const float* v    = (const float*)d_in[2];
    const float* W    = (const float*)d_in[3];
    const float* bias = (const float*)d_in[4];
    float* out = (float*)d_out;

    const int M = 16384;
    const size_t elems = (size_t)M * 1024;

    // ws: projq (32MB f16) + attn_out (32MB f16). projk/projv parked inside
    // d_out (64MB fp32), consumed by attn before the final GEMM overwrites it.
    f16* projq = (f16*)d_ws;
    f16* attn  = projq + elems;
    f16* projk = (f16*)d_out;
    f16* projv = projk + elems;

    convert_w_kernel<<<512, 256, 0, stream>>>(W);
    dim3 gridc(8192, 1, 3);
    convert_x_kernel<<<gridc, 256, 0, stream>>>(q, k, v);

    dim3 gridp(M / 256, 1024 / 256, 3);  // fused q/k/v projections
    gemm_proj_kernel<<<gridp, 512, 0, stream>>>(bias, projq, projk, projv);
    attn_kernel<<<M / 4, 256, 0, stream>>>(projq, projk, projv, attn);
    dim3 gridf(M / 256, 1024 / 256);
    gemm_kernel<float><<<gridf, 512, 0, stream>>>(attn, bias, out);
}

// Round 6
// 415.573 us; speedup vs baseline: 1.1152x; 1.0741x over previous
//
#include <hip/hip_runtime.h>
#include <hip/hip_fp16.h>
#include <math.h>

typedef _Float16 f16;
typedef _Float16 half8_t __attribute__((ext_vector_type(8)));
typedef _Float16 half4_t __attribute__((ext_vector_type(4)));
typedef _Float16 half2_t __attribute__((ext_vector_type(2)));
typedef __fp16   fp16x2  __attribute__((ext_vector_type(2)));
typedef float    float4_t __attribute__((ext_vector_type(4)));

// Converted weights (f16), written once per call by convert_w_kernel.
__device__ f16 Wh[1024 * 1024];
// Converted q/k/v (f16), written by convert_x_kernel (96 MB static).
__device__ f16 Xh[3ul * 16777216];

__device__ __forceinline__ void gl_lds16(const void* g, void* l) {
    __builtin_amdgcn_global_load_lds(
        (const __attribute__((address_space(1))) void*)g,
        (__attribute__((address_space(3))) void*)l,
        16, 0, 0);
}

__device__ __forceinline__ half2_t pkrtz(float a, float b) {
    fp16x2 r = __builtin_amdgcn_cvt_pkrtz(a, b);
    return __builtin_bit_cast(half2_t, r);
}

__device__ __forceinline__ half8_t cvt8(float4_t lo, float4_t hi) {
    half2_t p0 = pkrtz(lo[0], lo[1]);
    half2_t p1 = pkrtz(lo[2], lo[3]);
    half2_t p2 = pkrtz(hi[0], hi[1]);
    half2_t p3 = pkrtz(hi[2], hi[3]);
    half8_t r;
    r[0] = p0[0]; r[1] = p0[1]; r[2] = p1[0]; r[3] = p1[1];
    r[4] = p2[0]; r[5] = p2[1]; r[6] = p3[0]; r[7] = p3[1];
    return r;
}

__global__ __launch_bounds__(256) void convert_w_kernel(const float* __restrict__ W) {
    const int i = (blockIdx.x * 256 + threadIdx.x) * 8;
    const float4_t a = *(const float4_t*)(W + i);
    const float4_t b = *(const float4_t*)(W + i + 4);
    half8_t h;  // RTN conversion (accuracy; this kernel is cold)
#pragma unroll
    for (int t = 0; t < 4; ++t) h[t] = (f16)a[t];
#pragma unroll
    for (int t = 0; t < 4; ++t) h[4 + t] = (f16)b[t];
    *(half8_t*)(Wh + i) = h;
}

// q/k/v f32 -> f16 (pkrtz).  Memory-bound: 192 MB read + 96 MB write.
__global__ __launch_bounds__(256) void convert_x_kernel(
    const float* __restrict__ q, const float* __restrict__ k,
    const float* __restrict__ v)
{
    const int z = blockIdx.z;
    const float* src = (z == 0) ? q : (z == 1) ? k : v;
    f16* dst = Xh + (size_t)z * 16777216;
    const size_t i = ((size_t)blockIdx.x * 256 + threadIdx.x) * 8;
    const float4_t a = *(const float4_t*)(src + i);
    const float4_t b = *(const float4_t*)(src + i + 4);
    *(half8_t*)(dst + i) = cvt8(a, b);
}

// ---------------------------------------------------------------------------
// 8-PHASE 256x256 GEMM (4 phases per BK=64 K-tile), 8 waves (512 thr),
// double-buffered LDS (128 KB), counted vmcnt(6) ONCE per K-tile.
// Schedule (tile u, buf c=u&1):
//   P0: stage B-half0 of tile u+1 (-> buf c^1); vmcnt(6); barrier;
//       ds_read A-m0(8)+B-n0(4); MFMA quad(m0,n0); barrier
//   P1: ds_read A-m1(8)+B-n1(4); stage B-half1 of u+1; barrier;
//       MFMA quad(m0,n1); lgkmcnt(0); barrier   <- WAR fence: ALL waves'
//       tile-u LDS reads architecturally complete before anyone stages P2
//   P2: stage A-half0 of tile u+2 (-> buf c, safe per fence); barrier;
//       MFMA quad(m1,n0); barrier
//   P3: stage A-half1 of u+2; barrier; MFMA quad(m1,n1); barrier
// vmcnt(6) invariant at P0: the 6 newest loads are exactly {A(u+1)h0,
// A(u+1)h1, B(u+1)h0} (2 each) -> all of tile u has landed.  Tail uses dead
// wrapped re-stages to keep the count invariant (m201 approach).
// LDS chunk swizzle (proven 0-conflict): slot s at row r holds chunk s^(r&7).
// ---------------------------------------------------------------------------

__device__ __forceinline__ void stage_half(const f16* __restrict__ base, f16* dst,
                                           int tid, int kt, int half) {
#pragma unroll
    for (int it = 2 * half; it < 2 * half + 2; ++it) {
        const int ch = tid + it * 512;
        const int r = ch >> 3, s = ch & 7;
        gl_lds16(base + (size_t)r * 1024 + kt + ((s ^ (r & 7)) << 3), dst + ch * 8);
    }
}

template <typename TC>
__device__ __forceinline__ void gemm_tile256(const f16* __restrict__ A,
                                             const float* __restrict__ bias,
                                             TC* __restrict__ C,
                                             int row0, int col0) {
    constexpr int K = 1024, N = 1024, NT = 16;  // NT = K/64
    __shared__ __align__(16) f16 smem[65536];  // 128 KB -> 1 block/CU
    f16* const Asb = smem;          // [2][16384]
    f16* const Bsb = smem + 32768;  // [2][16384]

    const int tid  = threadIdx.x;
    const int lane = tid & 63;
    const int wave = tid >> 6;
    const int wr   = wave >> 2;  // 0..1
    const int wc   = wave & 3;   // 0..3
    const int lrow = lane & 15;
    const int kq   = lane >> 4;  // 0..3

    const f16* const Ag = A + (size_t)row0 * K;
    const f16* const Bg = Wh + (size_t)col0 * K;

    float4_t acc[8][4];
#pragma unroll
    for (int i = 0; i < 8; ++i)
#pragma unroll
        for (int j = 0; j < 4; ++j)
            acc[i][j] = (float4_t){0.f, 0.f, 0.f, 0.f};

    // ---- prologue: tile0 fully (A0,A1,B0,B1) + tile1 A0,A1 (12 loads/thread)
    stage_half(Ag, Asb, tid, 0, 0);
    stage_half(Ag, Asb, tid, 0, 1);
    stage_half(Bg, Bsb, tid, 0, 0);
    stage_half(Bg, Bsb, tid, 0, 1);
    stage_half(Ag, Asb + 16384, tid, 64, 0);
    stage_half(Ag, Asb + 16384, tid, 64, 1);

    for (int u = 0; u < NT; ++u) {
        const int c = u & 1;
        const f16* const Ac = Asb + (c << 14);
        const f16* const Bc = Bsb + (c << 14);
        f16* const Bn = Bsb + ((c ^ 1) << 14);       // tile u+1's B buffer
        f16* const Af = Asb + (c << 14);             // tile u+2's A buffer (== Ac)
        const int k1 = ((u + 1) & (NT - 1)) * 64;    // wrapped: tail = dead re-stage
        const int k2 = ((u + 2) & (NT - 1)) * 64;

        half8_t afv[8][2], bfv[4][2];

        // ================= P0 =================
        stage_half(Bg, Bn, tid, k1, 0);                       // u+1 B-half0
        asm volatile("s_waitcnt vmcnt(6)" ::: "memory");      // tile u landed
        __builtin_amdgcn_s_barrier();                         // ...for all waves
#pragma unroll
        for (int i = 0; i < 4; ++i) {
            const int m = wr * 128 + i * 16 + lrow;
#pragma unroll
            for (int ks = 0; ks < 2; ++ks)
                afv[i][ks] = *(const half8_t*)(Ac + m * 64 + (((ks * 4 + kq) ^ (m & 7)) << 3));
        }
#pragma unroll
        for (int j = 0; j < 2; ++j) {
            const int n = wc * 64 + j * 16 + lrow;
#pragma unroll
            for (int ks = 0; ks < 2; ++ks)
                bfv[j][ks] = *(const half8_t*)(Bc + n * 64 + (((ks * 4 + kq) ^ (n & 7)) << 3));
        }
        __builtin_amdgcn_s_setprio(1);
#pragma unroll
        for (int i = 0; i < 4; ++i)
#pragma unroll
            for (int j = 0; j < 2; ++j)
#pragma unroll
                for (int ks = 0; ks < 2; ++ks)
                    acc[i][j] = __builtin_amdgcn_mfma_f32_16x16x32_f16(
                        afv[i][ks], bfv[j][ks], acc[i][j], 0, 0, 0);
        __builtin_amdgcn_s_setprio(0);
        __builtin_amdgcn_s_barrier();

        // ================= P1 =================
#pragma unroll
        for (int i = 4; i < 8; ++i) {
            const int m = wr * 128 + i * 16 + lrow;
#pragma unroll
            for (int ks = 0; ks < 2; ++ks)
                afv[i][ks] = *(const half8_t*)(Ac + m * 64 + (((ks * 4 + kq) ^ (m & 7)) << 3));
        }
#pragma unroll
        for (int j = 2; j < 4; ++j) {
            const int n = wc * 64 + j * 16 + lrow;
#pragma unroll
            for (int ks = 0; ks < 2; ++ks)
                bfv[j][ks] = *(const half8_t*)(Bc + n * 64 + (((ks * 4 + kq) ^ (n & 7)) << 3));
        }
        stage_half(Bg, Bn, tid, k1, 1);                       // u+1 B-half1
        __builtin_amdgcn_s_barrier();
        __builtin_amdgcn_s_setprio(1);
#pragma unroll
        for (int i = 0; i < 4; ++i)
#pragma unroll
            for (int j = 2; j < 4; ++j)
#pragma unroll
                for (int ks = 0; ks < 2; ++ks)
                    acc[i][j] = __builtin_amdgcn_mfma_f32_16x16x32_f16(
                        afv[i][ks], bfv[j][ks], acc[i][j], 0, 0, 0);
        __builtin_amdgcn_s_setprio(0);
        // WAR fence: every wave's tile-u ds_reads (P0+P1) complete before the
        // barrier, so P2's staging into buf c cannot race them.
        asm volatile("s_waitcnt lgkmcnt(0)" ::: "memory");
        __builtin_amdgcn_s_barrier();

        // ================= P2 =================
        stage_half(Ag, Af, tid, k2, 0);                       // u+2 A-half0 (buf c)
        __builtin_amdgcn_s_barrier();
        __builtin_amdgcn_s_setprio(1);
#pragma unroll
        for (int i = 4; i < 8; ++i)
#pragma unroll
            for (int j = 0; j < 2; ++j)
#pragma unroll
                for (int ks = 0; ks < 2; ++ks)
                    acc[i][j] = __builtin_amdgcn_mfma_f32_16x16x32_f16(
                        afv[i][ks], bfv[j][ks], acc[i][j], 0, 0, 0);
        __builtin_amdgcn_s_setprio(0);
        __builtin_amdgcn_s_barrier();

        // ================= P3 =================
        stage_half(Ag, Af, tid, k2, 1);                       // u+2 A-half1
        __builtin_amdgcn_s_barrier();
        __builtin_amdgcn_s_setprio(1);
#pragma unroll
        for (int i = 4; i < 8; ++i)
#pragma unroll
            for (int j = 2; j < 4; ++j)
#pragma unroll
                for (int ks = 0; ks < 2; ++ks)
                    acc[i][j] = __builtin_amdgcn_mfma_f32_16x16x32_f16(
                        afv[i][ks], bfv[j][ks], acc[i][j], 0, 0, 0);
        __builtin_amdgcn_s_setprio(0);
        __builtin_amdgcn_s_barrier();
    }
    asm volatile("s_waitcnt vmcnt(0)" ::: "memory");  // drain dead tail stages
    __builtin_amdgcn_s_barrier();                     // LDS now reusable

    const int ccol  = lane & 15;
    const int rbase = (lane >> 4) << 2;

    if constexpr (sizeof(TC) == 2) {
        // f16 epilogue via LDS: full 128-B line stores (fixes 1.8x write amp).
        // Cs[row][col ^ (((row>>2)&3)<<4)], self-inverse XOR, bank-spread.
        f16* const Cs = smem;  // 256 x 256 f16 = 128 KB
#pragma unroll
        for (int j = 0; j < 4; ++j) {
            const int gcol = wc * 64 + j * 16 + ccol;
            const float bv = bias[col0 + gcol];
#pragma unroll
            for (int i = 0; i < 8; ++i) {
                const int grow = wr * 128 + i * 16 + rbase;
                const int cx = gcol ^ (((grow >> 2) & 3) << 4);
#pragma unroll
                for (int r = 0; r < 4; ++r)
                    Cs[(grow + r) * 256 + cx] = (f16)(acc[i][j][r] + bv);
            }
        }
        __builtin_amdgcn_s_barrier();
#pragma unroll
        for (int p = 0; p < 16; ++p) {
            const int idx = tid + p * 512;
            const int row = idx >> 5;
            const int col = (idx & 31) * 8;
            const int cx  = col ^ (((row >> 2) & 3) << 4);
            const half8_t v = *(const half8_t*)(Cs + row * 256 + cx);
            *(half8_t*)((TC*)C + (size_t)(row0 + row) * N + col0 + col) = v;
        }
    } else {
        // f32 epilogue: 16-lane runs are 64 B -> already sector-aligned.
#pragma unroll
        for (int j = 0; j < 4; ++j) {
            const int gcol = col0 + wc * 64 + j * 16 + ccol;
            const float bv = bias[gcol];
#pragma unroll
            for (int i = 0; i < 8; ++i) {
#pragma unroll
                for (int r = 0; r < 4; ++r) {
                    const int grow = row0 + wr * 128 + i * 16 + rbase + r;
                    C[(size_t)grow * N + gcol] = (TC)(acc[i][j][r] + bv);
                }
            }
        }
    }
}

// Final GEMM: grid (64,4).  XCD swizzle, y-fastest virtual order (A-panel L2 reuse).
template <typename TC>
__global__ __launch_bounds__(512, 2) void gemm_kernel(
    const f16* __restrict__ A, const float* __restrict__ bias,
    TC* __restrict__ C) {
    const int f    = blockIdx.x + 64 * blockIdx.y;   // 0..255
    const int virt = (f & 7) * 32 + (f >> 3);        // bijective (256 % 8 == 0)
    gemm_tile256<TC>(A, bias, C, ((virt >> 2) & 63) * 256, (virt & 3) * 256);
}

// Fused q/k/v projection: grid (64,4,3); same swizzle idea over 768 blocks.
__global__ __launch_bounds__(512, 2) void gemm_proj_kernel(
    const float* __restrict__ bias,
    f16* __restrict__ cq, f16* __restrict__ ck, f16* __restrict__ cv) {
    const int f    = blockIdx.x + 64 * (blockIdx.y + 4 * blockIdx.z);  // 0..767
    const int virt = (f & 7) * 96 + (f >> 3);        // bijective (768 % 8 == 0)
    const int y = virt & 3, x = (virt >> 2) & 63, z = virt >> 8;
    f16* C = (z == 0) ? cq : (z == 1) ? ck : cv;
    gemm_tile256<f16>(Xh + (size_t)z * 16777216, bias, C, x * 256, y * 256);
}

// ---------------------------------------------------------------------------
// MFMA attention.  One wave per (b,s) pair, 4 pairs per block.
// Swapped QK^T: S[e][d] = sum_h K[h][e] Q[h][d] via mfma_f32_16x16x16f16.
// C-layout (g=l>>4, lc=l&15): S[e=16et+4g+r][d=16dt+lc] == PV A-fragment
// layout A[m=lc][k=4g+r] -- no transpose.  Softmax: 16 in-lane + 2 shfl_xor.
// Output staged through LDS -> 8 full 128-B lines per wave.
// ---------------------------------------------------------------------------
__global__ __launch_bounds__(256) void attn_kernel(
    const f16* __restrict__ pq, const f16* __restrict__ pk,
    const f16* __restrict__ pv, f16* __restrict__ outp)
{
    __shared__ __align__(16) f16 Qs[4][64][24];  // [wave][d][h] (transposed)
    __shared__ __align__(16) f16 Ks[4][64][24];  // [wave][e][h] (transposed)
    __shared__ __align__(16) f16 Vs[4][16][72];  // [wave][h][e]
    __shared__ __align__(16) f16 Os[4][64][24];  // [wave][d][h] output stage
    const int lane = threadIdx.x & 63;
    const int wave = threadIdx.x >> 6;
    const int p0 = blockIdx.x * 4;
    const int p = p0 + wave;
    const f16* qptr = pq + (size_t)p * 1024;
    const f16* kptr = pk + (size_t)p * 1024;
    const f16* vptr = pv + (size_t)p * 1024;

    {
        const int h  = lane >> 2;
        const int c0 = (lane & 3) << 4;
        const half8_t q0 = *(const half8_t*)(qptr + lane * 16);
        const half8_t q1 = *(const half8_t*)(qptr + lane * 16 + 8);
        const half8_t k0 = *(const half8_t*)(kptr + lane * 16);
        const half8_t k1 = *(const half8_t*)(kptr + lane * 16 + 8);
#pragma unroll
        for (int t = 0; t < 8; ++t) {
            Qs[wave][c0 + t][h]     = q0[t];
            Qs[wave][c0 + 8 + t][h] = q1[t];
            Ks[wave][c0 + t][h]     = k0[t];
            Ks[wave][c0 + 8 + t][h] = k1[t];
        }
        const half8_t v0 = *(const half8_t*)(vptr + lane * 16);
        const half8_t v1 = *(const half8_t*)(vptr + lane * 16 + 8);
        *(half8_t*)&Vs[wave][h][c0]     = v0;
        *(half8_t*)&Vs[wave][h][c0 + 8] = v1;
    }
    __syncthreads();

    const int g  = lane >> 4;   // 0..3
    const int lc = lane & 15;   // 0..15

    // ---- QK^T (swapped): 16 x mfma 16x16x16
    half4_t ka[4], qb[4];
#pragma unroll
    for (int t = 0; t < 4; ++t) {
        ka[t] = *(const half4_t*)&Ks[wave][16 * t + lc][4 * g];
        qb[t] = *(const half4_t*)&Qs[wave][16 * t + lc][4 * g];
    }
    float4_t s[4][4];  // [et][dt]
#pragma unroll
    for (int et = 0; et < 4; ++et)
#pragma unroll
        for (int dt = 0; dt < 4; ++dt)
            s[et][dt] = __builtin_amdgcn_mfma_f32_16x16x16f16(
                ka[et], qb[dt], (float4_t){0.f, 0.f, 0.f, 0.f}, 0, 0, 0);

    // ---- softmax over e for each of the 4 in-lane d-columns (d = 16dt+lc)
    float inv[4];
#pragma unroll
    for (int dt = 0; dt < 4; ++dt) {
        float m = s[0][dt][0];
#pragma unroll
        for (int et = 0; et < 4; ++et)
#pragma unroll
            for (int r = 0; r < 4; ++r) m = fmaxf(m, s[et][dt][r]);
        m = fmaxf(m, __shfl_xor(m, 16));
        m = fmaxf(m, __shfl_xor(m, 32));
        float sum = 0.f;
#pragma unroll
        for (int et = 0; et < 4; ++et)
#pragma unroll
            for (int r = 0; r < 4; ++r) {
                const float t = __expf((s[et][dt][r] - m) * 0.125f);
                s[et][dt][r] = t;
                sum += t;
            }
        sum += __shfl_xor(sum, 16);
        sum += __shfl_xor(sum, 32);
        inv[dt] = 1.f / sum;
    }

    // ---- P -> f16 A-fragments (inv folded in); layout identity: pa[kt][dt]
    half4_t pa[4][4];
#pragma unroll
    for (int kt = 0; kt < 4; ++kt)
#pragma unroll
        for (int dt = 0; dt < 4; ++dt) {
            const half2_t lo = pkrtz(s[kt][dt][0] * inv[dt], s[kt][dt][1] * inv[dt]);
            const half2_t hi = pkrtz(s[kt][dt][2] * inv[dt], s[kt][dt][3] * inv[dt]);
            half4_t f;
            f[0] = lo[0]; f[1] = lo[1]; f[2] = hi[0]; f[3] = hi[1];
            pa[kt][dt] = f;
        }

    // ---- PV: C2[d][h] = sum_e P[d][e] V[h][e]; 16 x mfma 16x16x16
    float4_t o[4];
#pragma unroll
    for (int dt = 0; dt < 4; ++dt) o[dt] = (float4_t){0.f, 0.f, 0.f, 0.f};
#pragma unroll
    for (int kt = 0; kt < 4; ++kt) {
        const half4_t vb = *(const half4_t*)&Vs[wave][lc][16 * kt + 4 * g];
#pragma unroll
        for (int dt = 0; dt < 4; ++dt)
            o[dt] = __builtin_amdgcn_mfma_f32_16x16x16f16(pa[kt][dt], vb, o[dt], 0, 0, 0);
    }

    // ---- stage output: C2 col = h = lc, row(d) = 16dt + 4g + r
#pragma unroll
    for (int dt = 0; dt < 4; ++dt)
#pragma unroll
        for (int r = 0; r < 4; ++r)
            Os[wave][16 * dt + 4 * g + r][lc] = (f16)o[dt][r];
    __syncthreads();

    // ---- coalesced store: unit u = one 16-B chunk; wave covers 8 full lines
    const int b0 = p0 >> 11;
    const int s0 = p0 & 2047;
#pragma unroll
    for (int hf = 0; hf < 2; ++hf) {
        const int u  = threadIdx.x + hf * 256;
        const int d  = u >> 3;
        const int si = (u >> 1) & 3;
        const int uh = u & 1;
        const half8_t val = *(const half8_t*)&Os[si][d][uh * 8];
        f16* dst = outp + ((size_t)(b0 * 64 + d) * 2048 + (s0 + si)) * 16 + uh * 8;
        *(half8_t*)dst = val;
    }
}

extern "C" void kernel_launch(void* const* d_in, const int* in_sizes, int n_in,
                              void* d_out, int out_size, void* d_ws, size_t ws_size,
                              hipStream_t stream)
{
    const float* q    = (const float*)d_in[0];
    const float* k    = (const float*)d_in[1];
    const float* v    = (const float*)d_in[2];
    const float* W    = (const float*)d_in[3];
    const float* bias = (const float*)d_in[4];
    float* out = (float*)d_out;

    const int M = 16384;
    const size_t elems = (size_t)M * 1024;

    // ws: projq (32MB f16) + attn_out (32MB f16). projk/projv parked inside
    // d_out (64MB fp32), consumed by attn before the final GEMM overwrites it.
    f16* projq = (f16*)d_ws;
    f16* attn  = projq + elems;
    f16* projk = (f16*)d_out;
    f16* projv = projk + elems;

    convert_w_kernel<<<512, 256, 0, stream>>>(W);
    dim3 gridc(8192, 1, 3);
    convert_x_kernel<<<gridc, 256, 0, stream>>>(q, k, v);

    dim3 gridp(M / 256, 1024 / 256, 3);  // fused q/k/v projections
    gemm_proj_kernel<<<gridp, 512, 0, stream>>>(bias, projq, projk, projv);
    attn_kernel<<<M / 4, 256, 0, stream>>>(projq, projk, projv, attn);
    dim3 gridf(M / 256, 1024 / 256);
    gemm_kernel<float><<<gridf, 512, 0, stream>>>(attn, bias, out);
}

// Round 7
// 413.334 us; speedup vs baseline: 1.1212x; 1.0054x over previous
//
#include <hip/hip_runtime.h>
#include <hip/hip_fp16.h>
#include <math.h>

typedef _Float16 f16;
typedef _Float16 half8_t __attribute__((ext_vector_type(8)));
typedef _Float16 half4_t __attribute__((ext_vector_type(4)));
typedef _Float16 half2_t __attribute__((ext_vector_type(2)));
typedef __fp16   fp16x2  __attribute__((ext_vector_type(2)));
typedef float    float4_t __attribute__((ext_vector_type(4)));

// Converted weights (f16), written once per call by convert_w_kernel.
__device__ f16 Wh[1024 * 1024];
// Converted q/k/v (f16), written by convert_x_kernel (96 MB static).
__device__ f16 Xh[3ul * 16777216];

__device__ __forceinline__ void gl_lds16(const void* g, void* l) {
    __builtin_amdgcn_global_load_lds(
        (const __attribute__((address_space(1))) void*)g,
        (__attribute__((address_space(3))) void*)l,
        16, 0, 0);
}

__device__ __forceinline__ half2_t pkrtz(float a, float b) {
    fp16x2 r = __builtin_amdgcn_cvt_pkrtz(a, b);
    return __builtin_bit_cast(half2_t, r);
}

__device__ __forceinline__ half8_t cvt8(float4_t lo, float4_t hi) {
    half2_t p0 = pkrtz(lo[0], lo[1]);
    half2_t p1 = pkrtz(lo[2], lo[3]);
    half2_t p2 = pkrtz(hi[0], hi[1]);
    half2_t p3 = pkrtz(hi[2], hi[3]);
    half8_t r;
    r[0] = p0[0]; r[1] = p0[1]; r[2] = p1[0]; r[3] = p1[1];
    r[4] = p2[0]; r[5] = p2[1]; r[6] = p3[0]; r[7] = p3[1];
    return r;
}

__global__ __launch_bounds__(256) void convert_w_kernel(const float* __restrict__ W) {
    const int i = (blockIdx.x * 256 + threadIdx.x) * 8;
    const float4_t a = *(const float4_t*)(W + i);
    const float4_t b = *(const float4_t*)(W + i + 4);
    half8_t h;  // RTN conversion (accuracy; this kernel is cold)
#pragma unroll
    for (int t = 0; t < 4; ++t) h[t] = (f16)a[t];
#pragma unroll
    for (int t = 0; t < 4; ++t) h[4 + t] = (f16)b[t];
    *(half8_t*)(Wh + i) = h;
}

// q/k/v f32 -> f16 (pkrtz).  Memory-bound: 192 MB read + 96 MB write.
__global__ __launch_bounds__(256) void convert_x_kernel(
    const float* __restrict__ q, const float* __restrict__ k,
    const float* __restrict__ v)
{
    const int z = blockIdx.z;
    const float* src = (z == 0) ? q : (z == 1) ? k : v;
    f16* dst = Xh + (size_t)z * 16777216;
    const size_t i = ((size_t)blockIdx.x * 256 + threadIdx.x) * 8;
    const float4_t a = *(const float4_t*)(src + i);
    const float4_t b = *(const float4_t*)(src + i + 4);
    *(half8_t*)(dst + i) = cvt8(a, b);
}

// ---------------------------------------------------------------------------
// 8-PHASE 256x256 GEMM (4 phases per BK=64 K-tile), 8 waves (512 thr),
// double-buffered LDS (128 KB), ONE counted vmcnt(4) per K-tile.
// m201-ordered phases: {ds_read subtile ; stage half-tile ; barrier ;
// lgkmcnt(0)+sched_barrier ; setprio(1) MFMA x16 setprio(0) ; barrier}.
// Reads issued BEFORE the barrier hide their latency under barrier arrival.
// Quad order (m0n0),(m1n0),(m0n1),(m1n1) -> reads 12/8/4/0 per phase.
// Tile u, buf c=u&1:
//   P0: rd A-m0(8)+B-n0(4); stage B(u+1)h0 -> buf c^1; [bar;lgk0] Q(m0,n0)
//   P1: rd A-m1(8);         stage B(u+1)h1;            [bar;lgk0] Q(m1,n0)
//       (P1 close: all waves' A reads architecturally complete)
//   P2: rd B-n1(4);         stage A(u+2)h0 -> buf c;   [bar;lgk0] Q(m0,n1)
//   P3:                     stage A(u+2)h1;            [bar]      Q(m1,n1)
//       vmcnt(4); bar   <- A(u+1)+B(u+1) landed (FIFO), A(u+2) in flight
// Tail: wrapped dead re-stages keep the count invariant (m201 approach).
// LDS chunk swizzle (proven 0-conflict): slot s at row r holds chunk s^(r&7).
// stage_half half=0 -> rows 0..127, half=1 -> rows 128..255.
// ---------------------------------------------------------------------------

__device__ __forceinline__ void stage_half(const f16* __restrict__ base, f16* dst,
                                           int tid, int kt, int half) {
#pragma unroll
    for (int it = 2 * half; it < 2 * half + 2; ++it) {
        const int ch = tid + it * 512;
        const int r = ch >> 3, s = ch & 7;
        gl_lds16(base + (size_t)r * 1024 + kt + ((s ^ (r & 7)) << 3), dst + ch * 8);
    }
}

template <typename TC>
__device__ __forceinline__ void gemm_tile256(const f16* __restrict__ A,
                                             const float* __restrict__ bias,
                                             TC* __restrict__ C,
                                             int row0, int col0) {
    constexpr int K = 1024, N = 1024, NT = 16;  // NT = K/64
    __shared__ __align__(16) f16 smem[65536];  // 128 KB -> 1 block/CU
    f16* const Asb = smem;          // [2][16384]
    f16* const Bsb = smem + 32768;  // [2][16384]

    const int tid  = threadIdx.x;
    const int lane = tid & 63;
    const int wave = tid >> 6;
    const int wr   = wave >> 2;  // 0..1
    const int wc   = wave & 3;   // 0..3
    const int lrow = lane & 15;
    const int kq   = lane >> 4;  // 0..3

    const f16* const Ag = A + (size_t)row0 * K;
    const f16* const Bg = Wh + (size_t)col0 * K;

    float4_t acc[8][4];
#pragma unroll
    for (int i = 0; i < 8; ++i)
#pragma unroll
        for (int j = 0; j < 4; ++j)
            acc[i][j] = (float4_t){0.f, 0.f, 0.f, 0.f};

    // ---- prologue: tile0 fully + tile1 A (12 loads/thread); tile0 landed.
    stage_half(Ag, Asb, tid, 0, 0);
    stage_half(Ag, Asb, tid, 0, 1);
    stage_half(Bg, Bsb, tid, 0, 0);
    stage_half(Bg, Bsb, tid, 0, 1);
    stage_half(Ag, Asb + 16384, tid, 64, 0);
    stage_half(Ag, Asb + 16384, tid, 64, 1);
    asm volatile("s_waitcnt vmcnt(4)" ::: "memory");  // tile0 landed; A(1) in flight
    __builtin_amdgcn_s_barrier();

    for (int u = 0; u < NT; ++u) {
        const int c = u & 1;
        const f16* const Ac = Asb + (c << 14);
        const f16* const Bc = Bsb + (c << 14);
        f16* const Bn = Bsb + ((c ^ 1) << 14);       // tile u+1's B buffer
        f16* const Af = Asb + (c << 14);             // tile u+2's A buffer (== Ac)
        const int k1 = ((u + 1) & (NT - 1)) * 64;    // wrapped: tail = dead re-stage
        const int k2 = ((u + 2) & (NT - 1)) * 64;

        half8_t am0[4][2], am1[4][2], bn0[2][2], bn1[2][2];

        // ================= P0: rd A-m0 + B-n0 | stage B(u+1)h0 | Q(m0,n0)
#pragma unroll
        for (int i = 0; i < 4; ++i) {
            const int m = wr * 128 + i * 16 + lrow;
#pragma unroll
            for (int ks = 0; ks < 2; ++ks)
                am0[i][ks] = *(const half8_t*)(Ac + m * 64 + (((ks * 4 + kq) ^ (m & 7)) << 3));
        }
#pragma unroll
        for (int j = 0; j < 2; ++j) {
            const int n = wc * 64 + j * 16 + lrow;
#pragma unroll
            for (int ks = 0; ks < 2; ++ks)
                bn0[j][ks] = *(const half8_t*)(Bc + n * 64 + (((ks * 4 + kq) ^ (n & 7)) << 3));
        }
        stage_half(Bg, Bn, tid, k1, 0);
        __builtin_amdgcn_s_barrier();
        asm volatile("s_waitcnt lgkmcnt(0)" ::: "memory");
        __builtin_amdgcn_sched_barrier(0);
        __builtin_amdgcn_s_setprio(1);
#pragma unroll
        for (int i = 0; i < 4; ++i)
#pragma unroll
            for (int j = 0; j < 2; ++j)
#pragma unroll
                for (int ks = 0; ks < 2; ++ks)
                    acc[i][j] = __builtin_amdgcn_mfma_f32_16x16x32_f16(
                        am0[i][ks], bn0[j][ks], acc[i][j], 0, 0, 0);
        __builtin_amdgcn_s_setprio(0);
        __builtin_amdgcn_s_barrier();

        // ================= P1: rd A-m1 | stage B(u+1)h1 | Q(m1,n0)
#pragma unroll
        for (int i = 0; i < 4; ++i) {
            const int m = wr * 128 + (4 + i) * 16 + lrow;
#pragma unroll
            for (int ks = 0; ks < 2; ++ks)
                am1[i][ks] = *(const half8_t*)(Ac + m * 64 + (((ks * 4 + kq) ^ (m & 7)) << 3));
        }
        stage_half(Bg, Bn, tid, k1, 1);
        __builtin_amdgcn_s_barrier();
        asm volatile("s_waitcnt lgkmcnt(0)" ::: "memory");
        __builtin_amdgcn_sched_barrier(0);
        __builtin_amdgcn_s_setprio(1);
#pragma unroll
        for (int i = 0; i < 4; ++i)
#pragma unroll
            for (int j = 0; j < 2; ++j)
#pragma unroll
                for (int ks = 0; ks < 2; ++ks)
                    acc[4 + i][j] = __builtin_amdgcn_mfma_f32_16x16x32_f16(
                        am1[i][ks], bn0[j][ks], acc[4 + i][j], 0, 0, 0);
        __builtin_amdgcn_s_setprio(0);
        // close: every wave's A reads (P0+P1, LDS FIFO + lgkmcnt(0) above)
        // complete -> P2/P3 may stage A(u+2) into buf c.
        __builtin_amdgcn_s_barrier();

        // ================= P2: rd B-n1 | stage A(u+2)h0 | Q(m0,n1)
#pragma unroll
        for (int j = 0; j < 2; ++j) {
            const int n = wc * 64 + (2 + j) * 16 + lrow;
#pragma unroll
            for (int ks = 0; ks < 2; ++ks)
                bn1[j][ks] = *(const half8_t*)(Bc + n * 64 + (((ks * 4 + kq) ^ (n & 7)) << 3));
        }
        stage_half(Ag, Af, tid, k2, 0);
        __builtin_amdgcn_s_barrier();
        asm volatile("s_waitcnt lgkmcnt(0)" ::: "memory");
        __builtin_amdgcn_sched_barrier(0);
        __builtin_amdgcn_s_setprio(1);
#pragma unroll
        for (int i = 0; i < 4; ++i)
#pragma unroll
            for (int j = 0; j < 2; ++j)
#pragma unroll
                for (int ks = 0; ks < 2; ++ks)
                    acc[i][2 + j] = __builtin_amdgcn_mfma_f32_16x16x32_f16(
                        am0[i][ks], bn1[j][ks], acc[i][2 + j], 0, 0, 0);
        __builtin_amdgcn_s_setprio(0);
        __builtin_amdgcn_s_barrier();

        // ================= P3: stage A(u+2)h1 | Q(m1,n1) | vmcnt(4)
        stage_half(Ag, Af, tid, k2, 1);
        __builtin_amdgcn_s_barrier();
        __builtin_amdgcn_s_setprio(1);
#pragma unroll
        for (int i = 0; i < 4; ++i)
#pragma unroll
            for (int j = 0; j < 2; ++j)
#pragma unroll
                for (int ks = 0; ks < 2; ++ks)
                    acc[4 + i][2 + j] = __builtin_amdgcn_mfma_f32_16x16x32_f16(
                        am1[i][ks], bn1[j][ks], acc[4 + i][2 + j], 0, 0, 0);
        __builtin_amdgcn_s_setprio(0);
        // tile u+1 (A staged in u-1 P2/P3, B staged in u P0/P1) landed; only
        // A(u+2)'s 4 loads remain in flight (vmem completes in order).
        asm volatile("s_waitcnt vmcnt(4)" ::: "memory");
        __builtin_amdgcn_s_barrier();
    }
    asm volatile("s_waitcnt vmcnt(0)" ::: "memory");  // drain dead tail stages
    __builtin_amdgcn_s_barrier();                     // LDS now reusable

    const int ccol  = lane & 15;
    const int rbase = (lane >> 4) << 2;

    if constexpr (sizeof(TC) == 2) {
        // f16 epilogue via LDS: full 128-B line stores (write amp fixed, R6:
        // WRITE_SIZE exactly 96 MB).  Cs[row][col ^ (((row>>2)&3)<<4)].
        f16* const Cs = smem;  // 256 x 256 f16 = 128 KB
#pragma unroll
        for (int j = 0; j < 4; ++j) {
            const int gcol = wc * 64 + j * 16 + ccol;
            const float bv = bias[col0 + gcol];
#pragma unroll
            for (int i = 0; i < 8; ++i) {
                const int grow = wr * 128 + i * 16 + rbase;
                const int cx = gcol ^ (((grow >> 2) & 3) << 4);
#pragma unroll
                for (int r = 0; r < 4; ++r)
                    Cs[(grow + r) * 256 + cx] = (f16)(acc[i][j][r] + bv);
            }
        }
        __builtin_amdgcn_s_barrier();
#pragma unroll
        for (int p = 0; p < 16; ++p) {
            const int idx = tid + p * 512;
            const int row = idx >> 5;
            const int col = (idx & 31) * 8;
            const int cx  = col ^ (((row >> 2) & 3) << 4);
            const half8_t v = *(const half8_t*)(Cs + row * 256 + cx);
            *(half8_t*)((TC*)C + (size_t)(row0 + row) * N + col0 + col) = v;
        }
    } else {
        // f32 epilogue: 16-lane runs are 64 B -> already sector-aligned.
#pragma unroll
        for (int j = 0; j < 4; ++j) {
            const int gcol = col0 + wc * 64 + j * 16 + ccol;
            const float bv = bias[gcol];
#pragma unroll
            for (int i = 0; i < 8; ++i) {
#pragma unroll
                for (int r = 0; r < 4; ++r) {
                    const int grow = row0 + wr * 128 + i * 16 + rbase + r;
                    C[(size_t)grow * N + gcol] = (TC)(acc[i][j][r] + bv);
                }
            }
        }
    }
}

// Final GEMM: grid (64,4).  XCD swizzle, y-fastest virtual order (A-panel L2 reuse).
template <typename TC>
__global__ __launch_bounds__(512, 2) void gemm_kernel(
    const f16* __restrict__ A, const float* __restrict__ bias,
    TC* __restrict__ C) {
    const int f    = blockIdx.x + 64 * blockIdx.y;   // 0..255
    const int virt = (f & 7) * 32 + (f >> 3);        // bijective (256 % 8 == 0)
    gemm_tile256<TC>(A, bias, C, ((virt >> 2) & 63) * 256, (virt & 3) * 256);
}

// Fused q/k/v projection: grid (64,4,3); same swizzle idea over 768 blocks.
__global__ __launch_bounds__(512, 2) void gemm_proj_kernel(
    const float* __restrict__ bias,
    f16* __restrict__ cq, f16* __restrict__ ck, f16* __restrict__ cv) {
    const int f    = blockIdx.x + 64 * (blockIdx.y + 4 * blockIdx.z);  // 0..767
    const int virt = (f & 7) * 96 + (f >> 3);        // bijective (768 % 8 == 0)
    const int y = virt & 3, x = (virt >> 2) & 63, z = virt >> 8;
    f16* C = (z == 0) ? cq : (z == 1) ? ck : cv;
    gemm_tile256<f16>(Xh + (size_t)z * 16777216, bias, C, x * 256, y * 256);
}

// ---------------------------------------------------------------------------
// MFMA attention.  One wave per (b,s) pair, 4 pairs per block.
// Swapped QK^T: S[e][d] = sum_h K[h][e] Q[h][d] via mfma_f32_16x16x16f16.
// C-layout (g=l>>4, lc=l&15): S[e=16et+4g+r][d=16dt+lc] == PV A-fragment
// layout A[m=lc][k=4g+r] -- no transpose.  Softmax: 16 in-lane + 2 shfl_xor.
// Output staged through LDS -> 8 full 128-B lines per wave.
// ---------------------------------------------------------------------------
__global__ __launch_bounds__(256) void attn_kernel(
    const f16* __restrict__ pq, const f16* __restrict__ pk,
    const f16* __restrict__ pv, f16* __restrict__ outp)
{
    __shared__ __align__(16) f16 Qs[4][64][24];  // [wave][d][h] (transposed)
    __shared__ __align__(16) f16 Ks[4][64][24];  // [wave][e][h] (transposed)
    __shared__ __align__(16) f16 Vs[4][16][72];  // [wave][h][e]
    __shared__ __align__(16) f16 Os[4][64][24];  // [wave][d][h] output stage
    const int lane = threadIdx.x & 63;
    const int wave = threadIdx.x >> 6;
    const int p0 = blockIdx.x * 4;
    const int p = p0 + wave;
    const f16* qptr = pq + (size_t)p * 1024;
    const f16* kptr = pk + (size_t)p * 1024;
    const f16* vptr = pv + (size_t)p * 1024;

    {
        const int h  = lane >> 2;
        const int c0 = (lane & 3) << 4;
        const half8_t q0 = *(const half8_t*)(qptr + lane * 16);
        const half8_t q1 = *(const half8_t*)(qptr + lane * 16 + 8);
        const half8_t k0 = *(const half8_t*)(kptr + lane * 16);
        const half8_t k1 = *(const half8_t*)(kptr + lane * 16 + 8);
#pragma unroll
        for (int t = 0; t < 8; ++t) {
            Qs[wave][c0 + t][h]     = q0[t];
            Qs[wave][c0 + 8 + t][h] = q1[t];
            Ks[wave][c0 + t][h]     = k0[t];
            Ks[wave][c0 + 8 + t][h] = k1[t];
        }
        const half8_t v0 = *(const half8_t*)(vptr + lane * 16);
        const half8_t v1 = *(const half8_t*)(vptr + lane * 16 + 8);
        *(half8_t*)&Vs[wave][h][c0]     = v0;
        *(half8_t*)&Vs[wave][h][c0 + 8] = v1;
    }
    __syncthreads();

    const int g  = lane >> 4;   // 0..3
    const int lc = lane & 15;   // 0..15

    // ---- QK^T (swapped): 16 x mfma 16x16x16
    half4_t ka[4], qb[4];
#pragma unroll
    for (int t = 0; t < 4; ++t) {
        ka[t] = *(const half4_t*)&Ks[wave][16 * t + lc][4 * g];
        qb[t] = *(const half4_t*)&Qs[wave][16 * t + lc][4 * g];
    }
    float4_t s[4][4];  // [et][dt]
#pragma unroll
    for (int et = 0; et < 4; ++et)
#pragma unroll
        for (int dt = 0; dt < 4; ++dt)
            s[et][dt] = __builtin_amdgcn_mfma_f32_16x16x16f16(
                ka[et], qb[dt], (float4_t){0.f, 0.f, 0.f, 0.f}, 0, 0, 0);

    // ---- softmax over e for each of the 4 in-lane d-columns (d = 16dt+lc)
    float inv[4];
#pragma unroll
    for (int dt = 0; dt < 4; ++dt) {
        float m = s[0][dt][0];
#pragma unroll
        for (int et = 0; et < 4; ++et)
#pragma unroll
            for (int r = 0; r < 4; ++r) m = fmaxf(m, s[et][dt][r]);
        m = fmaxf(m, __shfl_xor(m, 16));
        m = fmaxf(m, __shfl_xor(m, 32));
        float sum = 0.f;
#pragma unroll
        for (int et = 0; et < 4; ++et)
#pragma unroll
            for (int r = 0; r < 4; ++r) {
                const float t = __expf((s[et][dt][r] - m) * 0.125f);
                s[et][dt][r] = t;
                sum += t;
            }
        sum += __shfl_xor(sum, 16);
        sum += __shfl_xor(sum, 32);
        inv[dt] = 1.f / sum;
    }

    // ---- P -> f16 A-fragments (inv folded in); layout identity: pa[kt][dt]
    half4_t pa[4][4];
#pragma unroll
    for (int kt = 0; kt < 4; ++kt)
#pragma unroll
        for (int dt = 0; dt < 4; ++dt) {
            const half2_t lo = pkrtz(s[kt][dt][0] * inv[dt], s[kt][dt][1] * inv[dt]);
            const half2_t hi = pkrtz(s[kt][dt][2] * inv[dt], s[kt][dt][3] * inv[dt]);
            half4_t f;
            f[0] = lo[0]; f[1] = lo[1]; f[2] = hi[0]; f[3] = hi[1];
            pa[kt][dt] = f;
        }

    // ---- PV: C2[d][h] = sum_e P[d][e] V[h][e]; 16 x mfma 16x16x16
    float4_t o[4];
#pragma unroll
    for (int dt = 0; dt < 4; ++dt) o[dt] = (float4_t){0.f, 0.f, 0.f, 0.f};
#pragma unroll
    for (int kt = 0; kt < 4; ++kt) {
        const half4_t vb = *(const half4_t*)&Vs[wave][lc][16 * kt + 4 * g];
#pragma unroll
        for (int dt = 0; dt < 4; ++dt)
            o[dt] = __builtin_amdgcn_mfma_f32_16x16x16f16(pa[kt][dt], vb, o[dt], 0, 0, 0);
    }

    // ---- stage output: C2 col = h = lc, row(d) = 16dt + 4g + r
#pragma unroll
    for (int dt = 0; dt < 4; ++dt)
#pragma unroll
        for (int r = 0; r < 4; ++r)
            Os[wave][16 * dt + 4 * g + r][lc] = (f16)o[dt][r];
    __syncthreads();

    // ---- coalesced store: unit u = one 16-B chunk; wave covers 8 full lines
    const int b0 = p0 >> 11;
    const int s0 = p0 & 2047;
#pragma unroll
    for (int hf = 0; hf < 2; ++hf) {
        const int u  = threadIdx.x + hf * 256;
        const int d  = u >> 3;
        const int si = (u >> 1) & 3;
        const int uh = u & 1;
        const half8_t val = *(const half8_t*)&Os[si][d][uh * 8];
        f16* dst = outp + ((size_t)(b0 * 64 + d) * 2048 + (s0 + si)) * 16 + uh * 8;
        *(half8_t*)dst = val;
    }
}

extern "C" void kernel_launch(void* const* d_in, const int* in_sizes, int n_in,
                              void* d_out, int out_size, void* d_ws, size_t ws_size,
                              hipStream_t stream)
{
    const float* q    = (const float*)d_in[0];
    const float* k    = (const float*)d_in[1];
    const float* v    = (const float*)d_in[2];
    const float* W    = (const float*)d_in[3];
    const float* bias = (const float*)d_in[4];
    float* out = (float*)d_out;

    const int M = 16384;
    const size_t elems = (size_t)M * 1024;

    // ws: projq (32MB f16) + attn_out (32MB f16). projk/projv parked inside
    // d_out (64MB fp32), consumed by attn before the final GEMM overwrites it.
    f16* projq = (f16*)d_ws;
    f16* attn  = projq + elems;
    f16* projk = (f16*)d_out;
    f16* projv = projk + elems;

    convert_w_kernel<<<512, 256, 0, stream>>>(W);
    dim3 gridc(8192, 1, 3);
    convert_x_kernel<<<gridc, 256, 0, stream>>>(q, k, v);

    dim3 gridp(M / 256, 1024 / 256, 3);  // fused q/k/v projections
    gemm_proj_kernel<<<gridp, 512, 0, stream>>>(bias, projq, projk, projv);
    attn_kernel<<<M / 4, 256, 0, stream>>>(projq, projk, projv, attn);
    dim3 gridf(M / 256, 1024 / 256);
    gemm_kernel<float><<<gridf, 512, 0, stream>>>(attn, bias, out);
}